// Round 1
// baseline (236.430 us; speedup 1.0000x reference)
//
#include <hip/hip_runtime.h>
#include <math.h>

#define N_PAT 16384
#define D_DIM 16384
#define NB    512                 // blocks in fused pass
#define TPB   1024                // threads per block
#define ROWS  (N_PAT / NB)        // 32 rows per block
#define VPT   (D_DIM / (TPB * 4)) // 4 float4 per thread
#define NWAVE (TPB / 64)          // 16 waves
#define EPSV  1e-8f

// Pass 1 (fused): per block, stream 32 rows of P once. For each row: dot(P_n,x),
// sumsq(P_n) via block reduction, sim, then online-softmax update of a
// register-resident partial weighted sum. Row data never leaves registers.
__global__ __launch_bounds__(TPB, 4) void fused_pass_kernel(
    const float* __restrict__ x, const float* __restrict__ P,
    float* __restrict__ accs, float* __restrict__ mlvals)
{
    __shared__ float red[NWAVE * 2];
    const int t = threadIdx.x;
    const int b = blockIdx.x;
    const int lane = t & 63;
    const int wid = t >> 6;
    const float4* __restrict__ x4 = (const float4*)x;
    const float4* __restrict__ P4 = (const float4*)P;

    float4 xv[VPT], acc[VPT], v[VPT];
    float xss = 0.f;
#pragma unroll
    for (int j = 0; j < VPT; ++j) {
        xv[j] = x4[t + TPB * j];
        acc[j] = make_float4(0.f, 0.f, 0.f, 0.f);
        xss += xv[j].x * xv[j].x + xv[j].y * xv[j].y
             + xv[j].z * xv[j].z + xv[j].w * xv[j].w;
    }
#pragma unroll
    for (int o = 32; o > 0; o >>= 1) xss += __shfl_down(xss, o, 64);
    if (lane == 0) red[wid] = xss;
    __syncthreads();
    float xn = 0.f;
#pragma unroll
    for (int w = 0; w < NWAVE; ++w) xn += red[w];
    const float inv_xn = 1.f / fmaxf(sqrtf(xn), EPSV);
    __syncthreads();

    float m = -INFINITY, l = 0.f;
    for (int r = 0; r < ROWS; ++r) {
        const size_t row = (size_t)b * ROWS + r;
        const float4* __restrict__ Pr = P4 + row * (size_t)(D_DIM / 4);
        // burst-issue all loads for this row (stay in flight together)
#pragma unroll
        for (int j = 0; j < VPT; ++j) v[j] = Pr[t + TPB * j];
        float dot = 0.f, ssq = 0.f;
#pragma unroll
        for (int j = 0; j < VPT; ++j) {
            dot = fmaf(v[j].x, xv[j].x, dot); dot = fmaf(v[j].y, xv[j].y, dot);
            dot = fmaf(v[j].z, xv[j].z, dot); dot = fmaf(v[j].w, xv[j].w, dot);
            ssq = fmaf(v[j].x, v[j].x, ssq);  ssq = fmaf(v[j].y, v[j].y, ssq);
            ssq = fmaf(v[j].z, v[j].z, ssq);  ssq = fmaf(v[j].w, v[j].w, ssq);
        }
#pragma unroll
        for (int o = 32; o > 0; o >>= 1) {
            dot += __shfl_down(dot, o, 64);
            ssq += __shfl_down(ssq, o, 64);
        }
        if (lane == 0) { red[wid * 2] = dot; red[wid * 2 + 1] = ssq; }
        __syncthreads();
        dot = 0.f; ssq = 0.f;
#pragma unroll
        for (int w = 0; w < NWAVE; ++w) { dot += red[w * 2]; ssq += red[w * 2 + 1]; }
        __syncthreads();   // red reused next row
        const float s = dot * inv_xn / fmaxf(sqrtf(ssq), EPSV);
        if (s > m) {       // wave-uniform branch (s, m uniform across block)
            const float sc = expf(m - s);   // expf(-inf)=0 handles first row
            l = fmaf(l, sc, 1.f);
#pragma unroll
            for (int j = 0; j < VPT; ++j) {
                acc[j].x = fmaf(acc[j].x, sc, v[j].x);
                acc[j].y = fmaf(acc[j].y, sc, v[j].y);
                acc[j].z = fmaf(acc[j].z, sc, v[j].z);
                acc[j].w = fmaf(acc[j].w, sc, v[j].w);
            }
            m = s;
        } else {
            const float p = expf(s - m);
            l += p;
#pragma unroll
            for (int j = 0; j < VPT; ++j) {
                acc[j].x = fmaf(p, v[j].x, acc[j].x);
                acc[j].y = fmaf(p, v[j].y, acc[j].y);
                acc[j].z = fmaf(p, v[j].z, acc[j].z);
                acc[j].w = fmaf(p, v[j].w, acc[j].w);
            }
        }
    }
    float4* __restrict__ oa = (float4*)(accs + (size_t)b * D_DIM);
#pragma unroll
    for (int j = 0; j < VPT; ++j) oa[t + TPB * j] = acc[j];
    if (t == 0) { mlvals[b] = m; mlvals[NB + b] = l; }
}

// Tiny: global max M over block maxes, global denom, per-block combine weight
// w_b = exp(m_b - M) / (denom * N). One block of NB threads.
__global__ void weights_kernel(const float* __restrict__ mlvals,
                               float* __restrict__ wvals)
{
    __shared__ float red[NB / 64];
    const int t = threadIdx.x, lane = t & 63, wid = t >> 6;
    const float m = mlvals[t];
    const float l = mlvals[NB + t];
    float mm = m;
#pragma unroll
    for (int o = 32; o > 0; o >>= 1) mm = fmaxf(mm, __shfl_down(mm, o, 64));
    if (lane == 0) red[wid] = mm;
    __syncthreads();
    float M = -INFINITY;
#pragma unroll
    for (int w = 0; w < NB / 64; ++w) M = fmaxf(M, red[w]);
    __syncthreads();
    const float e = expf(m - M);
    float c = l * e;
#pragma unroll
    for (int o = 32; o > 0; o >>= 1) c += __shfl_down(c, o, 64);
    if (lane == 0) red[wid] = c;
    __syncthreads();
    float denom = 0.f;
#pragma unroll
    for (int w = 0; w < NB / 64; ++w) denom += red[w];
    wvals[t] = e / (denom * (float)N_PAT);
}

// out[d] = sum_b w_b * accs[b][d]
__global__ void combine_kernel(const float* __restrict__ accs,
                               const float* __restrict__ wvals,
                               float* __restrict__ out)
{
    const int d = blockIdx.x * blockDim.x + threadIdx.x;
    float s = 0.f;
#pragma unroll 8
    for (int bb = 0; bb < NB; ++bb)
        s = fmaf(wvals[bb], accs[(size_t)bb * D_DIM + d], s);
    out[d] = s;
}

extern "C" void kernel_launch(void* const* d_in, const int* in_sizes, int n_in,
                              void* d_out, int out_size, void* d_ws, size_t ws_size,
                              hipStream_t stream) {
    const float* x = (const float*)d_in[0];        // 128*128 = 16384 f32
    const float* P = (const float*)d_in[1];        // 16384*16384 f32
    float* out = (float*)d_out;                    // 16384 f32

    float* accs   = (float*)d_ws;                  // NB * D floats = 32 MB
    float* mlvals = accs + (size_t)NB * D_DIM;     // 2*NB floats (m then l)
    float* wvals  = mlvals + 2 * NB;               // NB floats

    fused_pass_kernel<<<NB, TPB, 0, stream>>>(x, P, accs, mlvals);
    weights_kernel<<<1, NB, 0, stream>>>(mlvals, wvals);
    combine_kernel<<<D_DIM / 64, 64, 0, stream>>>(accs, wvals, out);
}